// Round 4
// baseline (2368.978 us; speedup 1.0000x reference)
//
#include <hip/hip_runtime.h>

// ---------------------------------------------------------------------------
// TypeNet: 3 branches x (BN1 -> flattened LSTM (2048 steps) -> BN2 -> LSTM (2048 steps))
// H = 128, gates = 512. Recurrence via mfma_f32_16x16x32_f16 (f32 accum).
// Round 4: 8 waves (2 per SIMD) so one wave's epilogue/LDS/trans latency is
// hidden under the sibling wave's MFMA issue (m114 co-scheduling). Each wave
// owns one 16-row m-tile per gate; epilogue select is 1-of-4 regs (12
// cndmask); acc zero-init folded into a zero-C first MFMA.
// ---------------------------------------------------------------------------

typedef _Float16 half8 __attribute__((ext_vector_type(8)));
typedef float float4_t __attribute__((ext_vector_type(4)));

__device__ __forceinline__ float fast_exp(float x) {
  return __builtin_amdgcn_exp2f(x * 1.44269504f);
}
__device__ __forceinline__ float fast_rcp(float x) { return __builtin_amdgcn_rcpf(x); }
__device__ __forceinline__ float sigm(float x) { return fast_rcp(1.0f + fast_exp(-x)); }
__device__ __forceinline__ float tanh_fast(float x) {
  return 1.0f - 2.0f * fast_rcp(1.0f + fast_exp(2.0f * x));
}

// LDS-visibility-only barrier: no vmcnt drain (global stores/loads in flight).
__device__ __forceinline__ void lds_barrier() {
  asm volatile("s_waitcnt lgkmcnt(0)\n\ts_barrier" ::: "memory");
}

// 1-of-4 register select by rr bits — 3 v_cndmask.
__device__ __forceinline__ float gsel4(float4_t a, bool r1, bool r2) {
  const float x = r1 ? a[1] : a[0];
  const float y = r1 ? a[3] : a[2];
  return r2 ? y : x;
}

// ---------------------------------------------------------------------------
// K1: BN1 over branch slice [128,16,3]; writes xbn[br][s=t*128+b][d].
// ---------------------------------------------------------------------------
__global__ __launch_bounds__(128) void bn1_kernel(const float* __restrict__ x,
                                                  const float* __restrict__ g1,
                                                  const float* __restrict__ b1,
                                                  float* __restrict__ xbn) {
  const int br = blockIdx.x >> 4;
  const int t  = blockIdx.x & 15;
  const int b  = threadIdx.x;
  const float* px = x + (b * 48 + br * 16 + t) * 3;
  const float v0 = px[0], v1 = px[1], v2 = px[2];
  float s  = v0 + v1 + v2;
  float ss = v0 * v0 + v1 * v1 + v2 * v2;
  for (int off = 32; off; off >>= 1) {
    s  += __shfl_down(s, off);
    ss += __shfl_down(ss, off);
  }
  __shared__ float red[4];
  if ((threadIdx.x & 63) == 0) {
    red[(threadIdx.x >> 6) * 2]     = s;
    red[(threadIdx.x >> 6) * 2 + 1] = ss;
  }
  __syncthreads();
  const float S = red[0] + red[2], SS = red[1] + red[3];
  const float mean = S * (1.0f / 384.0f);
  const float var  = SS * (1.0f / 384.0f) - mean * mean;
  const float rstd = rsqrtf(var + 1e-5f);
  const float a  = g1[t] * rstd;
  const float sh = b1[t] - mean * a;
  float* dst = xbn + br * 6144 + (t * 128 + b) * 3;
  dst[0] = v0 * a + sh;
  dst[1] = v1 * a + sh;
  dst[2] = v2 * a + sh;
}

// ---------------------------------------------------------------------------
// K3a: BN2 stats per (branch, channel) over 2048 elems of H1.
// ---------------------------------------------------------------------------
__global__ __launch_bounds__(256) void bn2stats_kernel(const float* __restrict__ H1,
                                                       float* __restrict__ stats) {
  const int br = blockIdx.x >> 7;
  const int ch = blockIdx.x & 127;
  const float* base = H1 + (size_t)br * 262144 + ch * 128;
  float s = 0.f, ss = 0.f;
  for (int k = threadIdx.x; k < 2048; k += 256) {
    const int t1 = k >> 7, h = k & 127;
    const float v = base[t1 * 16384 + h];
    s += v;
    ss += v * v;
  }
  for (int off = 32; off; off >>= 1) {
    s  += __shfl_down(s, off);
    ss += __shfl_down(ss, off);
  }
  __shared__ float red[8];
  if ((threadIdx.x & 63) == 0) {
    red[(threadIdx.x >> 6) * 2]     = s;
    red[(threadIdx.x >> 6) * 2 + 1] = ss;
  }
  __syncthreads();
  if (threadIdx.x == 0) {
    const float S  = red[0] + red[2] + red[4] + red[6];
    const float SS = red[1] + red[3] + red[5] + red[7];
    const float mean = S * (1.0f / 2048.0f);
    const float var  = SS * (1.0f / 2048.0f) - mean * mean;
    stats[(br * 128 + ch) * 2]     = mean;
    stats[(br * 128 + ch) * 2 + 1] = rsqrtf(var + 1e-5f);
  }
}

// ---------------------------------------------------------------------------
// K3b: G2x[br][s2][g] = Wih2 @ BN2(H1) + bih2 + bhh2, one block per (br, t2).
// ---------------------------------------------------------------------------
__global__ __launch_bounds__(256) void g2x_kernel(
    const float* __restrict__ H1, const float* __restrict__ stats,
    const float* __restrict__ g2, const float* __restrict__ b2v,
    const float* __restrict__ Wih2, const float* __restrict__ bih2,
    const float* __restrict__ bhh2, float* __restrict__ G2x) {
  const int br = blockIdx.x >> 7;
  const int t2 = blockIdx.x & 127;
  __shared__ float xh[2048];
  __shared__ float wt[64 * 129];
  const float mean = stats[(br * 128 + t2) * 2];
  const float rstd = stats[(br * 128 + t2) * 2 + 1];
  const float a  = g2[t2] * rstd;
  const float sh = b2v[t2] - mean * a;
  for (int e = threadIdx.x; e < 2048; e += 256) {
    const int b2 = e >> 7, d = e & 127;
    xh[e] = H1[(size_t)br * 262144 + (size_t)(b2 * 128 + t2) * 128 + d] * a + sh;
  }
  const int gl  = threadIdx.x & 63;
  const int b2b = (threadIdx.x >> 6) * 4;
  for (int gt = 0; gt < 8; ++gt) {
    __syncthreads();
    for (int e = threadIdx.x; e < 8192; e += 256)
      wt[(e >> 7) * 129 + (e & 127)] = Wih2[gt * 8192 + e];
    __syncthreads();
    float a0 = 0.f, a1 = 0.f, a2 = 0.f, a3 = 0.f;
    for (int d = 0; d < 128; ++d) {
      const float w = wt[gl * 129 + d];
      a0 += w * xh[(b2b + 0) * 128 + d];
      a1 += w * xh[(b2b + 1) * 128 + d];
      a2 += w * xh[(b2b + 2) * 128 + d];
      a3 += w * xh[(b2b + 3) * 128 + d];
    }
    const int g   = gt * 64 + gl;
    const float bb = bih2[g] + bhh2[g];
    float* dst = G2x + ((size_t)br * 2048 + t2 * 16) * 512 + g;
    dst[(b2b + 0) * 512] = a0 + bb;
    dst[(b2b + 1) * 512] = a1 + bb;
    dst[(b2b + 2) * 512] = a2 + bb;
    dst[(b2b + 3) * 512] = a3 + bb;
  }
}

// ---------------------------------------------------------------------------
// K2/K4: the recurrence. 1 block/branch, 8 waves (2/SIMD). Wave w owns, for
// each gate, Whh rows gate*128 + w*16 + (0..15) — one m-tile per gate, so
// afrag[gate][kt] (4x4) and acc[gate] (4 regs). Lane's acc regs hold D rows
// quad*4+r (all 16 cols equal). Lane's h index j = w*16 + quad*4 + (l15&3);
// gate value = 1-of-4 reg select. One lgkm-only barrier per step.
// ---------------------------------------------------------------------------
template <int LAYER>
__global__ __launch_bounds__(512, 1) void lstm_kernel(
    const float* __restrict__ Whh, const float* __restrict__ Wih,
    const float* __restrict__ bih, const float* __restrict__ bhh,
    const float* __restrict__ h0s, const float* __restrict__ c0s,
    const float* __restrict__ xbn, const float* __restrict__ G2x,
    float* __restrict__ H1, float* __restrict__ outp) {
  const int br   = blockIdx.x;
  const int tid  = threadIdx.x;
  const int wave = tid >> 6;
  const int lane = tid & 63;
  const int quad = lane >> 4;
  const int l15  = lane & 15;
  const bool r1 = (l15 & 1) != 0;
  const bool r2 = (l15 & 2) != 0;
  const bool store_lane = (l15 & 12) == 0;
  const int j = wave * 16 + quad * 4 + (l15 & 3);  // this lane's h index

  __shared__ __align__(16) _Float16 h_sh[2][128];
  __shared__ float xs[(LAYER == 1) ? 6144 : 64];

  // ---- preload Whh as f16 A-fragments: one m-tile per gate ----
  half8 afrag[4][4];
#pragma unroll
  for (int g = 0; g < 4; ++g) {
    const int row = g * 128 + wave * 16 + l15;
#pragma unroll
    for (int kt = 0; kt < 4; ++kt) {
      const float* src = Whh + row * 128 + kt * 32 + quad * 8;
      half8 f;
#pragma unroll
      for (int jj = 0; jj < 8; ++jj) f[jj] = (_Float16)src[jj];
      afrag[g][kt] = f;
    }
  }

  if (LAYER == 1) {
    for (int i = tid; i < 6144; i += 512) xs[i] = xbn[br * 6144 + i];
  }

  const int s0 = 2 * br + (LAYER - 1);
  float c = c0s[s0 * 128 + j];  // duplicated lanes hold identical state
  float bi = 0.f, bf = 0.f, bg = 0.f, bo = 0.f;
  float wxi[3] = {0, 0, 0}, wxf[3] = {0, 0, 0}, wxg[3] = {0, 0, 0}, wxo[3] = {0, 0, 0};
  if (LAYER == 1) {
    bi = bih[j] + bhh[j];
    bf = bih[128 + j] + bhh[128 + j];
    bg = bih[256 + j] + bhh[256 + j];
    bo = bih[384 + j] + bhh[384 + j];
#pragma unroll
    for (int d = 0; d < 3; ++d) {
      wxi[d] = Wih[j * 3 + d];
      wxf[d] = Wih[(128 + j) * 3 + d];
      wxg[d] = Wih[(256 + j) * 3 + d];
      wxo[d] = Wih[(384 + j) * 3 + d];
    }
  }
  if (tid < 128) h_sh[0][tid] = (_Float16)h0s[s0 * 128 + tid];

  // LAYER 2: depth-2 register prefetch of G2x gate rows (bias folded in).
  const float* gbase =
      (LAYER == 2) ? (G2x + (size_t)br * 2048 * 512 + j) : (const float*)nullptr;
  float c0g = 0.f, c1g = 0.f, c2g = 0.f, c3g = 0.f;
  float n0g = 0.f, n1g = 0.f, n2g = 0.f, n3g = 0.f;
  if (LAYER == 2) {
    c0g = gbase[0];   c1g = gbase[128]; c2g = gbase[256]; c3g = gbase[384];
    n0g = gbase[512]; n1g = gbase[640]; n2g = gbase[768]; n3g = gbase[896];
  }

  const float4_t zacc = {0.f, 0.f, 0.f, 0.f};
  __syncthreads();  // once; full drain fine

#pragma unroll 2
  for (int s = 0; s < 2048; ++s) {
    // prefetch step s+2 (hidden under MFMA; no barrier drains it)
    float p0 = 0.f, p1 = 0.f, p2 = 0.f, p3 = 0.f;
    if (LAYER == 2) {
      if (s + 2 < 2048) {
        const float* gp = gbase + (size_t)(s + 2) * 512;
        p0 = gp[0]; p1 = gp[128]; p2 = gp[256]; p3 = gp[384];
      }
    }

    const _Float16* hcur = h_sh[s & 1];
    half8 bfrag[4];
#pragma unroll
    for (int kt = 0; kt < 4; ++kt)
      bfrag[kt] = *reinterpret_cast<const half8*>(&hcur[kt * 32 + quad * 8]);

    // x / G2x term — independent of h; overlaps MFMA issue
    float xt_i, xt_f, xt_g, xt_o;
    if (LAYER == 1) {
      const float x0 = xs[s * 3], x1 = xs[s * 3 + 1], x2 = xs[s * 3 + 2];
      xt_i = bi + wxi[0] * x0 + wxi[1] * x1 + wxi[2] * x2;
      xt_f = bf + wxf[0] * x0 + wxf[1] * x1 + wxf[2] * x2;
      xt_g = bg + wxg[0] * x0 + wxg[1] * x1 + wxg[2] * x2;
      xt_o = bo + wxo[0] * x0 + wxo[1] * x1 + wxo[2] * x2;
    } else {
      xt_i = c0g; xt_f = c1g; xt_g = c2g; xt_o = c3g;
    }

    float4_t acc[4];
#pragma unroll
    for (int g = 0; g < 4; ++g)  // zero-C first MFMA (no per-step acc zeroing)
      acc[g] = __builtin_amdgcn_mfma_f32_16x16x32_f16(afrag[g][0], bfrag[0], zacc, 0, 0, 0);
#pragma unroll
    for (int kt = 1; kt < 4; ++kt)
#pragma unroll
      for (int g = 0; g < 4; ++g)
        acc[g] = __builtin_amdgcn_mfma_f32_16x16x32_f16(afrag[g][kt], bfrag[kt], acc[g], 0, 0, 0);

    const float gi = gsel4(acc[0], r1, r2) + xt_i;
    const float gf = gsel4(acc[1], r1, r2) + xt_f;
    const float gg = gsel4(acc[2], r1, r2) + xt_g;
    const float go = gsel4(acc[3], r1, r2) + xt_o;

    const float iv = sigm(gi);
    const float fv = sigm(gf);
    const float gv = tanh_fast(gg);
    const float ov = sigm(go);
    c = fv * c + iv * gv;
    const float hv = ov * tanh_fast(c);

    if (store_lane) {
      h_sh[(s + 1) & 1][j] = (_Float16)hv;
      if (LAYER == 1)
        H1[((size_t)br * 2048 + (size_t)s) * 128 + j] = hv;
      else
        outp[(size_t)br * 262144 + (size_t)s * 128 + j] = hv;
    }
    if (LAYER == 2) {
      c0g = n0g; c1g = n1g; c2g = n2g; c3g = n3g;
      n0g = p0;  n1g = p1;  n2g = p2;  n3g = p3;
    }
    lds_barrier();  // h broadcast; lgkm-only
  }
}

// ---------------------------------------------------------------------------
// Workspace layout (floats): xbn@0 (18432) | H1@18432 (786432) |
// stats@804864 (768) | G2x@805632 (3145728)
// ---------------------------------------------------------------------------
extern "C" void kernel_launch(void* const* d_in, const int* in_sizes, int n_in,
                              void* d_out, int out_size, void* d_ws, size_t ws_size,
                              hipStream_t stream) {
  const float* x    = (const float*)d_in[0];
  const float* g1   = (const float*)d_in[1];
  const float* b1   = (const float*)d_in[2];
  const float* Wih1 = (const float*)d_in[3];
  const float* Whh1 = (const float*)d_in[4];
  const float* bih1 = (const float*)d_in[5];
  const float* bhh1 = (const float*)d_in[6];
  const float* g2   = (const float*)d_in[7];
  const float* b2   = (const float*)d_in[8];
  const float* Wih2 = (const float*)d_in[9];
  const float* Whh2 = (const float*)d_in[10];
  const float* bih2 = (const float*)d_in[11];
  const float* bhh2 = (const float*)d_in[12];
  const float* h0s  = (const float*)d_in[13];
  const float* c0s  = (const float*)d_in[14];

  float* ws   = (float*)d_ws;
  float* xbn  = ws;
  float* H1b  = ws + 18432;
  float* st   = ws + 18432 + 786432;
  float* G2xb = st + 768;
  float* outp = (float*)d_out;

  bn1_kernel<<<48, 128, 0, stream>>>(x, g1, b1, xbn);
  lstm_kernel<1><<<3, 512, 0, stream>>>(Whh1, Wih1, bih1, bhh1, h0s, c0s, xbn,
                                        nullptr, H1b, nullptr);
  bn2stats_kernel<<<384, 256, 0, stream>>>(H1b, st);
  g2x_kernel<<<384, 256, 0, stream>>>(H1b, st, g2, b2, Wih2, bih2, bhh2, G2xb);
  lstm_kernel<2><<<3, 512, 0, stream>>>(Whh2, nullptr, bih2, bhh2, h0s, c0s,
                                        nullptr, G2xb, nullptr, outp);
}

// Round 5
// 2345.283 us; speedup vs baseline: 1.0101x; 1.0101x over previous
//
#include <hip/hip_runtime.h>

// ---------------------------------------------------------------------------
// TypeNet: 3 branches x (BN1 -> flattened LSTM (2048 steps) -> BN2 -> LSTM (2048 steps))
// H = 128, gates = 512. Recurrence via mfma_f32_16x16x32_f16 (f32 accum).
// Round 5: both layers' input gate terms precomputed into packed f16x4
// buffers (G1x/G2x, biases folded) -> one dwordx2 load per step; kt MFMA
// chain split depth 4 -> 2; minimal per-step VALU; one lgkm-only barrier.
// ---------------------------------------------------------------------------

typedef _Float16 half8 __attribute__((ext_vector_type(8)));
typedef _Float16 half4_t __attribute__((ext_vector_type(4)));
typedef float float4_t __attribute__((ext_vector_type(4)));

__device__ __forceinline__ float fast_exp(float x) {
  return __builtin_amdgcn_exp2f(x * 1.44269504f);
}
__device__ __forceinline__ float fast_rcp(float x) { return __builtin_amdgcn_rcpf(x); }
__device__ __forceinline__ float sigm(float x) { return fast_rcp(1.0f + fast_exp(-x)); }
__device__ __forceinline__ float tanh_fast(float x) {
  return 1.0f - 2.0f * fast_rcp(1.0f + fast_exp(2.0f * x));
}

// LDS-visibility-only barrier: no vmcnt drain (global stores/loads in flight).
__device__ __forceinline__ void lds_barrier() {
  asm volatile("s_waitcnt lgkmcnt(0)\n\ts_barrier" ::: "memory");
}

// 1-of-4 register select by rr bits — 3 v_cndmask.
__device__ __forceinline__ float gsel4(float4_t a, bool r1, bool r2) {
  const float x = r1 ? a[1] : a[0];
  const float y = r1 ? a[3] : a[2];
  return r2 ? y : x;
}

// ---------------------------------------------------------------------------
// K1: BN1 over branch slice [128,16,3]; writes xbn[br][s=t*128+b][d].
// ---------------------------------------------------------------------------
__global__ __launch_bounds__(128) void bn1_kernel(const float* __restrict__ x,
                                                  const float* __restrict__ g1,
                                                  const float* __restrict__ b1,
                                                  float* __restrict__ xbn) {
  const int br = blockIdx.x >> 4;
  const int t  = blockIdx.x & 15;
  const int b  = threadIdx.x;
  const float* px = x + (b * 48 + br * 16 + t) * 3;
  const float v0 = px[0], v1 = px[1], v2 = px[2];
  float s  = v0 + v1 + v2;
  float ss = v0 * v0 + v1 * v1 + v2 * v2;
  for (int off = 32; off; off >>= 1) {
    s  += __shfl_down(s, off);
    ss += __shfl_down(ss, off);
  }
  __shared__ float red[4];
  if ((threadIdx.x & 63) == 0) {
    red[(threadIdx.x >> 6) * 2]     = s;
    red[(threadIdx.x >> 6) * 2 + 1] = ss;
  }
  __syncthreads();
  const float S = red[0] + red[2], SS = red[1] + red[3];
  const float mean = S * (1.0f / 384.0f);
  const float var  = SS * (1.0f / 384.0f) - mean * mean;
  const float rstd = rsqrtf(var + 1e-5f);
  const float a  = g1[t] * rstd;
  const float sh = b1[t] - mean * a;
  float* dst = xbn + br * 6144 + (t * 128 + b) * 3;
  dst[0] = v0 * a + sh;
  dst[1] = v1 * a + sh;
  dst[2] = v2 * a + sh;
}

// ---------------------------------------------------------------------------
// K1b: G1x[br][s][j] = packed f16x4 {i,f,g,o} = Wih1 @ xbn[s] + bih1 + bhh1.
// 256 threads = 2 s x 128 j; grid 3 x 1024.
// ---------------------------------------------------------------------------
__global__ __launch_bounds__(256) void g1x_kernel(const float* __restrict__ xbn,
                                                  const float* __restrict__ Wih1,
                                                  const float* __restrict__ bih1,
                                                  const float* __restrict__ bhh1,
                                                  half4_t* __restrict__ G1x) {
  const int br = blockIdx.x >> 10;
  const int sp = blockIdx.x & 1023;
  const int s  = sp * 2 + (threadIdx.x >> 7);
  const int j  = threadIdx.x & 127;
  const float* px = xbn + br * 6144 + s * 3;
  const float x0 = px[0], x1 = px[1], x2 = px[2];
  half4_t outv;
#pragma unroll
  for (int g = 0; g < 4; ++g) {
    const int row = g * 128 + j;
    const float a = bih1[row] + bhh1[row] + Wih1[row * 3] * x0 +
                    Wih1[row * 3 + 1] * x1 + Wih1[row * 3 + 2] * x2;
    outv[g] = (_Float16)a;
  }
  G1x[(size_t)(br * 2048 + s) * 128 + j] = outv;
}

// ---------------------------------------------------------------------------
// K3a: BN2 stats per (branch, channel) over 2048 elems of H1.
// ---------------------------------------------------------------------------
__global__ __launch_bounds__(256) void bn2stats_kernel(const float* __restrict__ H1,
                                                       float* __restrict__ stats) {
  const int br = blockIdx.x >> 7;
  const int ch = blockIdx.x & 127;
  const float* base = H1 + (size_t)br * 262144 + ch * 128;
  float s = 0.f, ss = 0.f;
  for (int k = threadIdx.x; k < 2048; k += 256) {
    const int t1 = k >> 7, h = k & 127;
    const float v = base[t1 * 16384 + h];
    s += v;
    ss += v * v;
  }
  for (int off = 32; off; off >>= 1) {
    s  += __shfl_down(s, off);
    ss += __shfl_down(ss, off);
  }
  __shared__ float red[8];
  if ((threadIdx.x & 63) == 0) {
    red[(threadIdx.x >> 6) * 2]     = s;
    red[(threadIdx.x >> 6) * 2 + 1] = ss;
  }
  __syncthreads();
  if (threadIdx.x == 0) {
    const float S  = red[0] + red[2] + red[4] + red[6];
    const float SS = red[1] + red[3] + red[5] + red[7];
    const float mean = S * (1.0f / 2048.0f);
    const float var  = SS * (1.0f / 2048.0f) - mean * mean;
    stats[(br * 128 + ch) * 2]     = mean;
    stats[(br * 128 + ch) * 2 + 1] = rsqrtf(var + 1e-5f);
  }
}

// ---------------------------------------------------------------------------
// K3b: G2x (packed f16x4 per (s2,j)) = Wih2 @ BN2(H1) + bih2 + bhh2.
// One block per (br, t2); results staged in LDS, then packed write.
// ---------------------------------------------------------------------------
__global__ __launch_bounds__(256) void g2x_kernel(
    const float* __restrict__ H1, const float* __restrict__ stats,
    const float* __restrict__ g2, const float* __restrict__ b2v,
    const float* __restrict__ Wih2, const float* __restrict__ bih2,
    const float* __restrict__ bhh2, half4_t* __restrict__ G2x) {
  const int br = blockIdx.x >> 7;
  const int t2 = blockIdx.x & 127;
  __shared__ float xh[2048];          // [16 b2][128 d]
  __shared__ float wt[64 * 129];      // 64 g-rows, padded
  __shared__ half4_t res[2048];       // [16 b2][128 j] packed gates (16 KB)
  const float mean = stats[(br * 128 + t2) * 2];
  const float rstd = stats[(br * 128 + t2) * 2 + 1];
  const float a  = g2[t2] * rstd;
  const float sh = b2v[t2] - mean * a;
  for (int e = threadIdx.x; e < 2048; e += 256) {
    const int b2 = e >> 7, d = e & 127;
    xh[e] = H1[(size_t)br * 262144 + (size_t)(b2 * 128 + t2) * 128 + d] * a + sh;
  }
  const int gl  = threadIdx.x & 63;
  const int b2b = (threadIdx.x >> 6) * 4;
  for (int gt = 0; gt < 8; ++gt) {
    __syncthreads();
    for (int e = threadIdx.x; e < 8192; e += 256)
      wt[(e >> 7) * 129 + (e & 127)] = Wih2[gt * 8192 + e];
    __syncthreads();
    float a0 = 0.f, a1 = 0.f, a2 = 0.f, a3 = 0.f;
    for (int d = 0; d < 128; ++d) {
      const float w = wt[gl * 129 + d];
      a0 += w * xh[(b2b + 0) * 128 + d];
      a1 += w * xh[(b2b + 1) * 128 + d];
      a2 += w * xh[(b2b + 2) * 128 + d];
      a3 += w * xh[(b2b + 3) * 128 + d];
    }
    const int g    = gt * 64 + gl;
    const int gate = g >> 7;
    const int j    = g & 127;
    const float bb = bih2[g] + bhh2[g];
    res[(b2b + 0) * 128 + j][gate] = (_Float16)(a0 + bb);
    res[(b2b + 1) * 128 + j][gate] = (_Float16)(a1 + bb);
    res[(b2b + 2) * 128 + j][gate] = (_Float16)(a2 + bb);
    res[(b2b + 3) * 128 + j][gate] = (_Float16)(a3 + bb);
  }
  __syncthreads();
  half4_t* dst = G2x + (size_t)(br * 2048 + t2 * 16) * 128;
  for (int e = threadIdx.x; e < 2048; e += 256) dst[e] = res[e];
}

// ---------------------------------------------------------------------------
// K2/K4: the recurrence (unified both layers). 1 block/branch, 8 waves.
// Wave w owns gate rows g*128 + w*16 + (0..15); lane j = w*16+quad*4+(l15&3);
// kt chain split lo(kt0,1)/hi(kt2,3); gates from acc via 4 adds + 3 cndmask;
// x-term from packed f16x4 Gx with depth-2 register prefetch; one lgkm-only
// barrier per step.
// ---------------------------------------------------------------------------
__global__ __launch_bounds__(512, 1) void lstm_kernel(
    const float* __restrict__ Whh, const float* __restrict__ h0s,
    const float* __restrict__ c0s, const half4_t* __restrict__ Gx,
    float* __restrict__ outp, int layer) {
  const int br   = blockIdx.x;
  const int tid  = threadIdx.x;
  const int wave = tid >> 6;
  const int lane = tid & 63;
  const int quad = lane >> 4;
  const int l15  = lane & 15;
  const bool r1 = (l15 & 1) != 0;
  const bool r2 = (l15 & 2) != 0;
  const bool store_lane = (l15 & 12) == 0;
  const int j = wave * 16 + quad * 4 + (l15 & 3);

  __shared__ __align__(16) _Float16 h_sh[2][128];

  // ---- preload Whh as f16 A-fragments: one m-tile per gate ----
  half8 afrag[4][4];
#pragma unroll
  for (int g = 0; g < 4; ++g) {
    const int row = g * 128 + wave * 16 + l15;
#pragma unroll
    for (int kt = 0; kt < 4; ++kt) {
      const float* src = Whh + row * 128 + kt * 32 + quad * 8;
      half8 f;
#pragma unroll
      for (int jj = 0; jj < 8; ++jj) f[jj] = (_Float16)src[jj];
      afrag[g][kt] = f;
    }
  }

  const int slot = 2 * br + layer;
  float c = c0s[slot * 128 + j];  // duplicated lanes hold identical state
  if (tid < 128) h_sh[0][tid] = (_Float16)h0s[slot * 128 + tid];

  // packed gate-preact stream; depth-2 register prefetch
  const half4_t* gb = Gx + (size_t)br * 2048 * 128 + j;
  half4_t cur = gb[0];
  half4_t nxt = gb[128];
  const half4_t* gpf = gb + 2 * 128;
  float* op = outp + (size_t)br * 262144 + j;

  const float4_t zacc = {0.f, 0.f, 0.f, 0.f};
  __syncthreads();  // once; full drain fine

#pragma unroll 2
  for (int s = 0; s < 2048; ++s) {
    // bfrag reads first — the post-barrier latency we must pay
    const _Float16* hcur = h_sh[s & 1];
    half8 bfrag[4];
#pragma unroll
    for (int kt = 0; kt < 4; ++kt)
      bfrag[kt] = *reinterpret_cast<const half8*>(&hcur[kt * 32 + quad * 8]);

    const half4_t pf = *gpf;       // prefetch s+2 (off critical path)
    if (s < 2045) gpf += 128;      // clamp: last iters re-read s=2047 (harmless)

    // split kt chains: depth 2 each
    float4_t lo[4], hi[4];
#pragma unroll
    for (int g = 0; g < 4; ++g) {
      lo[g] = __builtin_amdgcn_mfma_f32_16x16x32_f16(afrag[g][0], bfrag[0], zacc, 0, 0, 0);
      hi[g] = __builtin_amdgcn_mfma_f32_16x16x32_f16(afrag[g][2], bfrag[2], zacc, 0, 0, 0);
    }
#pragma unroll
    for (int g = 0; g < 4; ++g) {
      lo[g] = __builtin_amdgcn_mfma_f32_16x16x32_f16(afrag[g][1], bfrag[1], lo[g], 0, 0, 0);
      hi[g] = __builtin_amdgcn_mfma_f32_16x16x32_f16(afrag[g][3], bfrag[3], hi[g], 0, 0, 0);
    }

    const float xt_i = (float)cur[0];
    const float xt_f = (float)cur[1];
    const float xt_g = (float)cur[2];
    const float xt_o = (float)cur[3];

    const float4_t s0 = lo[0] + hi[0];
    const float4_t s1 = lo[1] + hi[1];
    const float4_t s2 = lo[2] + hi[2];
    const float4_t s3 = lo[3] + hi[3];

    const float gi = gsel4(s0, r1, r2) + xt_i;
    const float gf = gsel4(s1, r1, r2) + xt_f;
    const float gg = gsel4(s2, r1, r2) + xt_g;
    const float go = gsel4(s3, r1, r2) + xt_o;

    const float iv = sigm(gi);
    const float fv = sigm(gf);
    const float gv = tanh_fast(gg);
    const float ov = sigm(go);
    c = fv * c + iv * gv;
    const float hv = ov * tanh_fast(c);

    h_sh[(s + 1) & 1][j] = (_Float16)hv;  // dup lanes write same value: benign
    if (store_lane) *op = hv;
    op += 128;

    cur = nxt;
    nxt = pf;
    lds_barrier();  // h broadcast; lgkm-only
  }
}

// ---------------------------------------------------------------------------
// Workspace layout (floats):
//   xbn   [3][2048][3]            @ 0        (18432)
//   H1    [3][2048][128]          @ 18432    (786432)
//   stats [3][128][2]             @ 804864   (768)
//   G1x   [3][2048][128] f16x4    @ 805632   (1572864 floats)
//   G2x   [3][2048][128] f16x4    @ 2378496  (1572864 floats)   total ~15.8 MB
// ---------------------------------------------------------------------------
extern "C" void kernel_launch(void* const* d_in, const int* in_sizes, int n_in,
                              void* d_out, int out_size, void* d_ws, size_t ws_size,
                              hipStream_t stream) {
  const float* x    = (const float*)d_in[0];
  const float* g1   = (const float*)d_in[1];
  const float* b1   = (const float*)d_in[2];
  const float* Wih1 = (const float*)d_in[3];
  const float* Whh1 = (const float*)d_in[4];
  const float* bih1 = (const float*)d_in[5];
  const float* bhh1 = (const float*)d_in[6];
  const float* g2   = (const float*)d_in[7];
  const float* b2   = (const float*)d_in[8];
  const float* Wih2 = (const float*)d_in[9];
  const float* Whh2 = (const float*)d_in[10];
  const float* bih2 = (const float*)d_in[11];
  const float* bhh2 = (const float*)d_in[12];
  const float* h0s  = (const float*)d_in[13];
  const float* c0s  = (const float*)d_in[14];

  float* ws   = (float*)d_ws;
  float* xbn  = ws;
  float* H1b  = ws + 18432;
  float* st   = ws + 18432 + 786432;
  half4_t* G1xb = (half4_t*)(ws + 805632);
  half4_t* G2xb = (half4_t*)(ws + 2378496);
  float* outp = (float*)d_out;

  bn1_kernel<<<48, 128, 0, stream>>>(x, g1, b1, xbn);
  g1x_kernel<<<3072, 256, 0, stream>>>(xbn, Wih1, bih1, bhh1, G1xb);
  lstm_kernel<<<3, 512, 0, stream>>>(Whh1, h0s, c0s, G1xb, H1b, 0);
  bn2stats_kernel<<<384, 256, 0, stream>>>(H1b, st);
  g2x_kernel<<<384, 256, 0, stream>>>(H1b, st, g2, b2, Wih2, bih2, bhh2, G2xb);
  lstm_kernel<<<3, 512, 0, stream>>>(Whh2, h0s, c0s, G2xb, outp, 1);
}